// Round 14
// baseline (340.182 us; speedup 1.0000x reference)
//
#include <hip/hip_runtime.h>
#include <math.h>

#define NN 50000
#define NE 800000
#define TE (NE + NN)
#define HC 128
#define NEG_SLOPE 0.2f
#define EPSV 1e-5f
#define NBUCK 64
#define GGRID 782          // (NN+63)/64 blocks for gemm_dual part of init_k
#define WTB 128            // wtrans blocks
#define CB ((TE + 255) / 256)   // fused count blocks
#define ZB 52              // zero blocks
#define ZERO_N4 18644      // float4 count of zero region (298304 B = stats 98304 + cnt 200000)

typedef __attribute__((ext_vector_type(8))) short bf16x8;
typedef __attribute__((ext_vector_type(4))) float f32x4;
union BfU { uint4 u; bf16x8 b; };

__device__ __forceinline__ unsigned short f2bf(float x) {
    unsigned u = __float_as_uint(x);
    unsigned r = (u + 0x7fff + ((u >> 16) & 1)) >> 16;  // RNE
    return (unsigned short)r;
}

// ---------------- zero_k: stats buckets + cnt (must precede fused count) ----------------

__global__ __launch_bounds__(256) void zero_k(float4* __restrict__ zero4) {
    float4 zv; zv.x = zv.y = zv.z = zv.w = 0.f;
    for (int i = blockIdx.x * 256 + threadIdx.x; i < ZERO_N4; i += ZB * 256)
        zero4[i] = zv;
}

// ---------------- CSR build ----------------

__global__ __launch_bounds__(1024) void scan1_k(const int* __restrict__ cnt,
                                                int* __restrict__ excl,
                                                int* __restrict__ aux) {
    __shared__ int wsum[16];
    int tid = threadIdx.x;
    int gid = blockIdx.x * 1024 + tid;
    int lane = tid & 63, wid = tid >> 6;
    int v = (gid < NN) ? cnt[gid] : 0;
    int x = v;
#pragma unroll
    for (int off = 1; off < 64; off <<= 1) {
        int t = __shfl_up(x, off, 64);
        if (lane >= off) x += t;
    }
    if (lane == 63) wsum[wid] = x;
    __syncthreads();
    if (wid == 0 && lane < 16) {
        int y = wsum[lane];
#pragma unroll
        for (int off = 1; off < 16; off <<= 1) {
            int t = __shfl_up(y, off, 64);
            if (lane >= off) y += t;
        }
        wsum[lane] = y;
    }
    __syncthreads();
    int base = (wid > 0) ? wsum[wid - 1] : 0;
    int incl = base + x;
    if (gid < NN) excl[gid] = incl - v;
    if (tid == 1023) aux[blockIdx.x] = incl;
}

__global__ __launch_bounds__(256) void scatter_k(const int* __restrict__ srcp,
                                                 const int* __restrict__ dstp,
                                                 const int* __restrict__ excl,
                                                 const int* __restrict__ aux,
                                                 const int* __restrict__ rank,
                                                 int* __restrict__ row_ptr,
                                                 int* __restrict__ col,
                                                 int nblk) {
    __shared__ int auxs[64];
    if (threadIdx.x < 64) {
        int lane = threadIdx.x;
        int v = (lane < nblk) ? aux[lane] : 0;
        int x = v;
#pragma unroll
        for (int off = 1; off < 64; off <<= 1) {
            int t = __shfl_up(x, off, 64);
            if (lane >= off) x += t;
        }
        auxs[lane] = x - v;
    }
    __syncthreads();
    int e = blockIdx.x * 256 + threadIdx.x;
    if (e >= TE) return;
    if (e <= NN) row_ptr[e] = (e == NN) ? TE : excl[e] + auxs[e >> 10];
    int s, d;
    if (e < NE) { s = srcp[e]; d = dstp[e]; } else { s = e - NE; d = s; }
    col[excl[d] + auxs[d >> 10] + rank[e]] = s << 8;
}

// ---- packed pair store (fp32 path, layer 1): slot 4*dd holds (ch d, ch d+32) ----
__device__ __forceinline__ void store_xlp(char* xlp, int row, int c0, const float* a) {
    unsigned hsel = (unsigned)c0 >> 6;
    unsigned dd = (unsigned)c0 & 31;
    unsigned sub = (c0 & 32) ? 2u : 0u;
    char* q = xlp + (size_t)row * 256 + hsel * 128 + 4 * dd + sub;
#pragma unroll
    for (int j = 0; j < 4; ++j)
        *(unsigned short*)(q + 4 * j) = f2bf(a[j]);
}

// ---------------- init_k: fused count FIRST (latency overlap), then wtrans, then gemm ----------------
// R13 showed init's 54 MB WRITE = 850k atomic line-RMWs (the floor); count blocks
// are scheduled first so their memory round-trips overlap the gemm compute wave.

__global__ __launch_bounds__(256) void init_k(const float* __restrict__ x,
                                              const float* __restrict__ Wl1,
                                              const float* __restrict__ Wr1,
                                              char* __restrict__ xlp,
                                              char* __restrict__ xrp,
                                              const float* __restrict__ Wl2,
                                              const float* __restrict__ Wr2,
                                              const float* __restrict__ Wl3,
                                              const float* __restrict__ Wr3,
                                              unsigned short* __restrict__ wt2,
                                              unsigned short* __restrict__ wt3,
                                              const int* __restrict__ dst,
                                              int* __restrict__ cnt,
                                              int* __restrict__ rank) {
    __shared__ float xs[3][72];
    __shared__ float ws[3][260];
    int b = blockIdx.x;
    int tid = threadIdx.x;

    if (b < CB) {
        // fused count: cnt zeroed by preceding zero_k dispatch
        int e = b * 256 + tid;
        if (e < TE) {
            int d = (e < NE) ? dst[e] : (e - NE);
            rank[e] = atomicAdd(&cnt[d], 1);
        }
        return;
    }
    if (b < CB + WTB) {
        int idx = (b - CB) * 256 + tid;
        int l = idx >> 14;
        int rem = idx & 16383;
        int k = rem >> 8;
        int c = rem & 255;
        const float* W = (l == 0) ? (c < 128 ? Wl2 : Wr2) : (c < 128 ? Wl3 : Wr3);
        float v = W[k * 128 + (c & 127)];
        unsigned short* wt = (l == 0) ? wt2 : wt3;
        wt[c * 64 + k] = f2bf(v);
        return;
    }

    // ---- gemm_dual body (K=3) ----
    int row0 = (b - CB - WTB) * 64;
    int row_t = (tid >> 5) * 8;
    int c0 = (tid & 31) * 4;
    const int K = 3;

    float acc0[8][4];
    float acc1[8][4];
#pragma unroll
    for (int i = 0; i < 8; ++i)
#pragma unroll
        for (int j = 0; j < 4; ++j) { acc0[i][j] = 0.f; acc1[i][j] = 0.f; }

    for (int i = tid; i < 64 * K; i += 256) {
        int r = i / K;
        int k = i - r * K;
        int row = row0 + r;
        xs[k][r] = (row < NN) ? x[(size_t)row * K + k] : 0.f;
    }
    for (int i = tid; i < K * 64; i += 256) {
        int k = i >> 6;
        int cq = i & 63;
        const float* srcp = (cq < 32) ? &Wl1[(size_t)k * 128 + cq * 4]
                                      : &Wr1[(size_t)k * 128 + (cq - 32) * 4];
        float4 v = *(const float4*)srcp;
        *(float4*)&ws[k][cq * 4] = v;
    }
    __syncthreads();
    for (int k = 0; k < K; ++k) {
        float4 a0 = *(float4*)&xs[k][row_t];
        float4 a1 = *(float4*)&xs[k][row_t + 4];
        float4 b0 = *(float4*)&ws[k][c0];
        float4 b1 = *(float4*)&ws[k][c0 + 128];
        float av[8] = {a0.x, a0.y, a0.z, a0.w, a1.x, a1.y, a1.z, a1.w};
        float bl[4] = {b0.x, b0.y, b0.z, b0.w};
        float br[4] = {b1.x, b1.y, b1.z, b1.w};
#pragma unroll
        for (int i = 0; i < 8; ++i)
#pragma unroll
            for (int j = 0; j < 4; ++j) {
                acc0[i][j] += av[i] * bl[j];
                acc1[i][j] += av[i] * br[j];
            }
    }
#pragma unroll
    for (int i = 0; i < 8; ++i) {
        int row = row0 + row_t + i;
        if (row < NN) {
            store_xlp(xlp, row, c0, acc0[i]);
            store_xlp(xrp, row, c0, acc1[i]);   // xr packed bf16, same layout as xlp
        }
    }
}

// ---- shared helper: reduce 64 stat buckets -> cf[128] ----
__device__ __forceinline__ void reduce_stats(const float* __restrict__ stats,
                                             const float* __restrict__ gw,
                                             const float* __restrict__ gb,
                                             const float* __restrict__ gm,
                                             float (*part)[128],
                                             float* __restrict__ cf_out) {
    int tid = threadIdx.x;
    int w = tid >> 6;
    int lane = tid & 63;
    float s = 0.f, s2 = 0.f;
    for (int b = 16 * w; b < 16 * w + 16; ++b) {
        s += stats[b * 128 + lane];
        s2 += stats[b * 128 + 64 + lane];
    }
    part[w][lane] = s;
    part[w][64 + lane] = s2;
    __syncthreads();
    if (tid < 64) {
        int c = tid;
        float sum = (part[0][c] + part[1][c]) + (part[2][c] + part[3][c]);
        float sum2 = (part[0][64 + c] + part[1][64 + c]) + (part[2][64 + c] + part[3][64 + c]);
        float inv_n = 1.f / (float)NN;
        float mu = sum * inv_n;
        float ex2 = sum2 * inv_n;
        float g = gm[c];
        float var = ex2 - 2.f * g * mu * mu + g * g * mu * mu;
        float rs = rsqrtf(var + EPSV);
        cf_out[c] = gw[c] * rs;
        cf_out[64 + c] = gb[c] - gw[c] * rs * g * mu;
    }
    __syncthreads();
}

// ---------------- MFMA bf16 GEMM; h input is packed bf16 (col c, c+32 per uint) ----------------

__global__ __launch_bounds__(256) void gemm_mfma(const unsigned* __restrict__ hbf,
                                                 const float* __restrict__ stats,
                                                 const float* __restrict__ gw,
                                                 const float* __restrict__ gb,
                                                 const float* __restrict__ gm,
                                                 const unsigned short* __restrict__ wt,
                                                 char* __restrict__ xlp,
                                                 char* __restrict__ xrp,
                                                 int n) {
    __shared__ unsigned short xs[64][72];
    __shared__ float part[4][128];
    __shared__ float cfS[128];
    int tid = threadIdx.x;
    int row0 = blockIdx.x * 64;

    reduce_stats(stats, gw, gb, gm, part, cfS);

    {
        int r = tid >> 2;
        int q = tid & 3;
        int row = row0 + r;
        unsigned pk[8];
        if (row < n) {
            const unsigned* hp = hbf + (size_t)row * 32 + (q & 1) * 16;
            uint4 u0 = *(const uint4*)(hp + 0);
            uint4 u1 = *(const uint4*)(hp + 4);
            uint4 u2 = *(const uint4*)(hp + 8);
            uint4 u3 = *(const uint4*)(hp + 12);
            unsigned hv[16] = {u0.x, u0.y, u0.z, u0.w, u1.x, u1.y, u1.z, u1.w,
                               u2.x, u2.y, u2.z, u2.w, u3.x, u3.y, u3.z, u3.w};
            bool hi = (q >> 1) != 0;
#pragma unroll
            for (int i = 0; i < 4; ++i) {
                float4 v;
                v.x = hi ? __uint_as_float(hv[4 * i + 0] & 0xffff0000u) : __uint_as_float(hv[4 * i + 0] << 16);
                v.y = hi ? __uint_as_float(hv[4 * i + 1] & 0xffff0000u) : __uint_as_float(hv[4 * i + 1] << 16);
                v.z = hi ? __uint_as_float(hv[4 * i + 2] & 0xffff0000u) : __uint_as_float(hv[4 * i + 2] << 16);
                v.w = hi ? __uint_as_float(hv[4 * i + 3] & 0xffff0000u) : __uint_as_float(hv[4 * i + 3] << 16);
                float4 cw = *(const float4*)&cfS[q * 16 + 4 * i];
                float4 cb = *(const float4*)&cfS[64 + q * 16 + 4 * i];
                float r0 = fmaxf(fmaf(cw.x, v.x, cb.x), 0.f);
                float r1 = fmaxf(fmaf(cw.y, v.y, cb.y), 0.f);
                float r2 = fmaxf(fmaf(cw.z, v.z, cb.z), 0.f);
                float r3 = fmaxf(fmaf(cw.w, v.w, cb.w), 0.f);
                pk[2 * i]     = (unsigned)f2bf(r0) | ((unsigned)f2bf(r1) << 16);
                pk[2 * i + 1] = (unsigned)f2bf(r2) | ((unsigned)f2bf(r3) << 16);
            }
        } else {
#pragma unroll
            for (int i = 0; i < 8; ++i) pk[i] = 0;
        }
        uint4* dst = (uint4*)&xs[r][q * 16];
        dst[0] = make_uint4(pk[0], pk[1], pk[2], pk[3]);
        dst[1] = make_uint4(pk[4], pk[5], pk[6], pk[7]);
    }
    __syncthreads();

    int w = tid >> 6;
    int lane = tid & 63;
    int m = lane & 15;
    int quad = lane >> 4;

    BfU a0, a1;
    a0.u = *(const uint4*)&xs[16 * w + m][quad * 8];
    a1.u = *(const uint4*)&xs[16 * w + m][32 + quad * 8];

    const char* wtb = (const char*)wt + (size_t)(m * 128 + quad * 16);

    f32x4 acc[16];
#pragma unroll
    for (int c = 0; c < 16; ++c) acc[c] = (f32x4){0.f, 0.f, 0.f, 0.f};
#pragma unroll
    for (int c = 0; c < 16; ++c) {
        BfU b0, b1;
        b0.u = *(const uint4*)(wtb + c * 2048);
        b1.u = *(const uint4*)(wtb + c * 2048 + 64);
        acc[c] = __builtin_amdgcn_mfma_f32_16x16x32_bf16(a0.b, b0.b, acc[c], 0, 0, 0);
        acc[c] = __builtin_amdgcn_mfma_f32_16x16x32_bf16(a1.b, b1.b, acc[c], 0, 0, 0);
    }

    int rbase = row0 + 16 * w + quad * 4;
    // xl (acc 0..7) and xr (acc 8..15) both stored packed: pair (c, c+2) -> (ch d, ch d+32)
#pragma unroll
    for (int pi = 0; pi < 4; ++pi) {
        int c = (pi & 1) + (pi >> 1) * 4;
        int head = pi >> 1;
        int dd = (pi & 1) * 16 + m;
#pragma unroll
        for (int r = 0; r < 4; ++r) {
            int row = rbase + r;
            if (row < n) {
                unsigned vl = (unsigned)f2bf(acc[c][r]) | ((unsigned)f2bf(acc[c + 2][r]) << 16);
                unsigned vr = (unsigned)f2bf(acc[c + 8][r]) | ((unsigned)f2bf(acc[c + 10][r]) << 16);
                *(unsigned*)(xlp + (size_t)row * 256 + head * 128 + 4 * dd) = vl;
                *(unsigned*)(xrp + (size_t)row * 256 + head * 128 + 4 * dd) = vr;
            }
        }
    }
}

// ---------------- coef_k: one block, stats buckets -> cf (for apply) ----------------

__global__ __launch_bounds__(256) void coef_k(const float* __restrict__ stats,
                                              const float* __restrict__ gw,
                                              const float* __restrict__ gb,
                                              const float* __restrict__ gm,
                                              float* __restrict__ cf) {
    __shared__ float part[4][128];
    reduce_stats(stats, gw, gb, gm, part, cf);
}

// ---------------- Attention: 16 lanes per edge, uint4 gather, packed bf16 xr ----------------

__device__ __forceinline__ void unpack8(uint4 q, float* l) {
    l[0] = __uint_as_float(q.x << 16);
    l[1] = __uint_as_float(q.x & 0xffff0000u);
    l[2] = __uint_as_float(q.y << 16);
    l[3] = __uint_as_float(q.y & 0xffff0000u);
    l[4] = __uint_as_float(q.z << 16);
    l[5] = __uint_as_float(q.z & 0xffff0000u);
    l[6] = __uint_as_float(q.w << 16);
    l[7] = __uint_as_float(q.w & 0xffff0000u);
}

// per-lane partial of logit: 0.6*sum(a*t) + 0.4*sum(a*|t|), t = l + xv
__device__ __forceinline__ float logit_part(const float* l, const float* xv, const float* av) {
    float u1 = 0.f, u2 = 0.f;
#pragma unroll
    for (int k = 0; k < 8; ++k) {
        float t = l[k] + xv[k];
        u1 = fmaf(av[k], t, u1);
        u2 = fmaf(av[k], fabsf(t), u2);
    }
    return fmaf(0.6f, u1, 0.4f * u2);
}

__device__ __forceinline__ float head_reduce(float x) {
    x += __int_as_float(__builtin_amdgcn_mov_dpp(__float_as_int(x), 0xB1, 0xF, 0xF, true)); // quad xor1
    x += __int_as_float(__builtin_amdgcn_mov_dpp(__float_as_int(x), 0x4E, 0xF, 0xF, true)); // quad xor2
    x += __shfl_xor(x, 4, 64);
    return x;
}

__device__ __forceinline__ void attn_pair(const char* __restrict__ xlp, int lp16,
                                          int off0, int off1, bool v0, bool v1,
                                          const float* xv, const float* av,
                                          float* o, float& zacc) {
    uint4 q0 = *(const uint4*)(xlp + (unsigned)(off0 + lp16));
    uint4 q1 = *(const uint4*)(xlp + (unsigned)(off1 + lp16));
    float l0[8], l1[8];
    unpack8(q0, l0);
    unpack8(q1, l1);
    float w0 = head_reduce(logit_part(l0, xv, av));
    float w1 = head_reduce(logit_part(l1, xv, av));
    float e0 = __expf(w0);
    float e1 = __expf(w1);
    if (!v0) e0 = 0.f;
    if (!v1) e1 = 0.f;
    zacc += e0 + e1;
#pragma unroll
    for (int k = 0; k < 8; ++k) o[k] = fmaf(e1, l1[k], fmaf(e0, l0[k], o[k]));
}

__global__ __launch_bounds__(256) void attn_k(const char* __restrict__ xlp,
                                              const char* __restrict__ xrp,
                                              const float* __restrict__ att,
                                              const float* __restrict__ bias,
                                              const int* __restrict__ row_ptr,
                                              const int* __restrict__ coloff,
                                              unsigned* __restrict__ hout,
                                              float* __restrict__ stats) {
    __shared__ float sb[4][64];
    int tid = threadIdx.x;
    int lane = tid & 63;
    int wv = tid >> 6;
    int node = blockIdx.x * 4 + wv;       // grid == NN/4 exactly
    int t16 = lane & 15;
    int slot = (lane >> 4) * 2;
    int head = t16 >> 3;
    int dd = (t16 & 7) * 4;
    int lp16 = t16 * 16;
    int cbase = head * 64 + dd;

    float xv[8];
    unpack8(*(const uint4*)(xrp + ((size_t)node << 8) + lp16), xv);
    float4 a0 = *(const float4*)(att + cbase);
    float4 a1 = *(const float4*)(att + cbase + 32);
    float av[8] = {a0.x, a1.x, a0.y, a1.y, a0.z, a1.z, a0.w, a1.w};

    float o[8];
#pragma unroll
    for (int k = 0; k < 8; ++k) o[k] = 0.f;
    float zacc = 0.f;

    int beg = __builtin_amdgcn_readfirstlane(row_ptr[node]);
    int end = __builtin_amdgcn_readfirstlane(row_ptr[node + 1]);

    int idx = beg;
    for (; idx + 8 <= end; idx += 8) {
        int off0 = coloff[idx + slot];
        int off1 = coloff[idx + slot + 1];
        attn_pair(xlp, lp16, off0, off1, true, true, xv, av, o, zacc);
    }
    if (idx < end) {
        int e1 = end - 1;
        int i0 = idx + slot, i1 = idx + slot + 1;
        int off0 = coloff[min(i0, e1)];
        int off1 = coloff[min(i1, e1)];
        attn_pair(xlp, lp16, off0, off1, i0 < end, i1 < end, xv, av, o, zacc);
    }

    // cross-group (bits 4,5) reduce for z and o; heads stay separate (bit 3)
    float z = zacc + __shfl_xor(zacc, 16, 64);
    z += __shfl_xor(z, 32, 64);
    float zi = 1.0f / z;
    float r[8];
#pragma unroll
    for (int k = 0; k < 8; ++k) {
        float v = o[k] + __shfl_xor(o[k], 16, 64);
        v += __shfl_xor(v, 32, 64);
        v *= zi;
        float p = __shfl_xor(v, 8, 64);   // partner head, same channels (l-order pairs)
        r[k] = 0.5f * (v + p);
    }
    if (lane < 8) {
        // r[] is in l-order: even k -> head0 ch dd+k/2, odd k -> head1 ch dd+k/2
        float4 b0 = *(const float4*)(bias + dd);
        float4 b1 = *(const float4*)(bias + dd + 32);
        float rl0 = r[0] + b0.x, rl1 = r[2] + b0.y, rl2 = r[4] + b0.z, rl3 = r[6] + b0.w;
        float rh0 = r[1] + b1.x, rh1 = r[3] + b1.y, rh2 = r[5] + b1.z, rh3 = r[7] + b1.w;
        unsigned pk0 = (unsigned)f2bf(rl0) | ((unsigned)f2bf(rh0) << 16);
        unsigned pk1 = (unsigned)f2bf(rl1) | ((unsigned)f2bf(rh1) << 16);
        unsigned pk2 = (unsigned)f2bf(rl2) | ((unsigned)f2bf(rh2) << 16);
        unsigned pk3 = (unsigned)f2bf(rl3) | ((unsigned)f2bf(rh3) << 16);
        *(uint4*)&hout[(size_t)node * 32 + dd] = make_uint4(pk0, pk1, pk2, pk3);
        *(float4*)&sb[wv][dd] = make_float4(rl0, rl1, rl2, rl3);
        *(float4*)&sb[wv][dd + 32] = make_float4(rh0, rh1, rh2, rh3);
    }
    __syncthreads();
    if (tid < 64) {
        int c = tid;
        float v0 = sb[0][c], v1 = sb[1][c], v2 = sb[2][c], v3 = sb[3][c];
        float s = (v0 + v1) + (v2 + v3);
        float s2 = fmaf(v0, v0, v1 * v1) + fmaf(v2, v2, v3 * v3);
        float* bkt = stats + (size_t)(blockIdx.x & (NBUCK - 1)) * 128;
        atomicAdd(&bkt[c], s);
        atomicAdd(&bkt[64 + c], s2);
    }
}

// ---------------- final GraphNorm apply + ReLU (unpack bf16 h, fp32 out) ----------------

__global__ __launch_bounds__(256) void apply_k(const unsigned* __restrict__ h,
                                               const float* __restrict__ cf,
                                               float* __restrict__ y) {
    int i = blockIdx.x * 256 + threadIdx.x;   // uint4 index, total NN*8
    if (i >= NN * 8) return;
    int node = i >> 3;
    int j = (i & 7) * 4;                      // laneh base 0,4,...,28
    uint4 u = *(const uint4*)(h + (size_t)node * 32 + j);
    float4 lo, hi;
    lo.x = __uint_as_float(u.x << 16); hi.x = __uint_as_float(u.x & 0xffff0000u);
    lo.y = __uint_as_float(u.y << 16); hi.y = __uint_as_float(u.y & 0xffff0000u);
    lo.z = __uint_as_float(u.z << 16); hi.z = __uint_as_float(u.z & 0xffff0000u);
    lo.w = __uint_as_float(u.w << 16); hi.w = __uint_as_float(u.w & 0xffff0000u);
    float4 cwl = *(const float4*)&cf[j];
    float4 cbl = *(const float4*)&cf[64 + j];
    float4 cwh = *(const float4*)&cf[32 + j];
    float4 cbh = *(const float4*)&cf[96 + j];
    float4 rl, rh;
    rl.x = fmaxf(fmaf(cwl.x, lo.x, cbl.x), 0.f);
    rl.y = fmaxf(fmaf(cwl.y, lo.y, cbl.y), 0.f);
    rl.z = fmaxf(fmaf(cwl.z, lo.z, cbl.z), 0.f);
    rl.w = fmaxf(fmaf(cwl.w, lo.w, cbl.w), 0.f);
    rh.x = fmaxf(fmaf(cwh.x, hi.x, cbh.x), 0.f);
    rh.y = fmaxf(fmaf(cwh.y, hi.y, cbh.y), 0.f);
    rh.z = fmaxf(fmaf(cwh.z, hi.z, cbh.z), 0.f);
    rh.w = fmaxf(fmaf(cwh.w, hi.w, cbh.w), 0.f);
    *(float4*)&y[(size_t)node * 64 + j] = rl;
    *(float4*)&y[(size_t)node * 64 + 32 + j] = rh;
}

// ---------------- launch ----------------

extern "C" void kernel_launch(void* const* d_in, const int* in_sizes, int n_in,
                              void* d_out, int out_size, void* d_ws, size_t ws_size,
                              hipStream_t stream) {
    const float* x0 = (const float*)d_in[0];
    const int* ei = (const int*)d_in[1];
    const int* srcp = ei;
    const int* dstp = ei + NE;

    const float* Wl[3], *Wr[3], *att[3], *bv[3], *gw[3], *gb[3], *gm[3];
    for (int l = 0; l < 3; ++l) {
        int base = 2 + 7 * l;
        Wl[l] = (const float*)d_in[base + 0];
        Wr[l] = (const float*)d_in[base + 1];
        att[l] = (const float*)d_in[base + 2];
        bv[l] = (const float*)d_in[base + 3];
        gw[l] = (const float*)d_in[base + 4];
        gb[l] = (const float*)d_in[base + 5];
        gm[l] = (const float*)d_in[base + 6];
    }

    char* p = (char*)d_ws;
    auto take = [&](size_t bytes) -> void* {
        void* r = (void*)p;
        p += (bytes + 255) & ~(size_t)255;
        return r;
    };
    char* xlp = (char*)take((size_t)NN * 256);
    char* xrp = (char*)take((size_t)NN * 256);             // packed bf16, same layout as xlp
    unsigned* hb = (unsigned*)take((size_t)NN * 32 * 4);   // packed bf16 hidden state
    char* zr = (char*)take(298304);
    float* stats = (float*)zr;
    int* cnt = (int*)(zr + 98304);
    int* excl = (int*)take((size_t)NN * 4);
    int* row_ptr = (int*)take((size_t)(NN + 1) * 4);
    int* rank = (int*)take((size_t)TE * 4);
    int* col = (int*)take((size_t)TE * 4);
    int* aux = (int*)take(64 * 4);
    float* cf3 = (float*)take(128 * 4);
    unsigned short* wt2 = (unsigned short*)take(16384 * 2);
    unsigned short* wt3 = (unsigned short*)take(16384 * 2);

    int nblk = (NN + 1023) / 1024;
    int egrid = (TE + 255) / 256;

    zero_k<<<ZB, 256, 0, stream>>>((float4*)zr);
    init_k<<<CB + WTB + GGRID, 256, 0, stream>>>(x0, Wl[0], Wr[0], xlp, xrp,
                                                 Wl[1], Wr[1], Wl[2], Wr[2],
                                                 wt2, wt3, dstp, cnt, rank);
    scan1_k<<<nblk, 1024, 0, stream>>>(cnt, excl, aux);
    scatter_k<<<egrid, 256, 0, stream>>>(srcp, dstp, excl, aux, rank, row_ptr, col, nblk);

    int ggrid = (NN + 63) / 64;
    int agrid = NN / 4;   // exact
    for (int l = 0; l < 3; ++l) {
        if (l > 0)
            gemm_mfma<<<ggrid, 256, 0, stream>>>(hb, stats + (size_t)(l - 1) * NBUCK * 128,
                                                 gw[l - 1], gb[l - 1], gm[l - 1],
                                                 (l == 1) ? wt2 : wt3, xlp, xrp, NN);
        attn_k<<<agrid, 256, 0, stream>>>(xlp, xrp, att[l], bv[l], row_ptr, col, hb,
                                          stats + (size_t)l * NBUCK * 128);
    }
    coef_k<<<1, 256, 0, stream>>>(stats + (size_t)2 * NBUCK * 128, gw[2], gb[2], gm[2], cf3);
    apply_k<<<(NN * 8 + 255) / 256, 256, 0, stream>>>(hb, cf3, (float*)d_out);
}

// Round 15
// 330.595 us; speedup vs baseline: 1.0290x; 1.0290x over previous
//
#include <hip/hip_runtime.h>
#include <math.h>

#define NN 50000
#define NE 800000
#define TE (NE + NN)
#define HC 128
#define NEG_SLOPE 0.2f
#define EPSV 1e-5f
#define NBUCK 64
#define GGRID 782          // (NN+63)/64 blocks for gemm_dual part of init_k
#define WTB 128            // wtrans blocks
#define CB ((TE + 255) / 256)   // fused count blocks
#define ZB 52              // zero blocks
#define ZERO_N4 18644      // float4 count of zero region (298304 B = stats 98304 + cnt 200000)

typedef __attribute__((ext_vector_type(8))) short bf16x8;
typedef __attribute__((ext_vector_type(4))) float f32x4;
union BfU { uint4 u; bf16x8 b; };

__device__ __forceinline__ unsigned short f2bf(float x) {
    unsigned u = __float_as_uint(x);
    unsigned r = (u + 0x7fff + ((u >> 16) & 1)) >> 16;  // RNE
    return (unsigned short)r;
}

// ---------------- zero_k: stats buckets + cnt (must precede fused count) ----------------

__global__ __launch_bounds__(256) void zero_k(float4* __restrict__ zero4) {
    float4 zv; zv.x = zv.y = zv.z = zv.w = 0.f;
    for (int i = blockIdx.x * 256 + threadIdx.x; i < ZERO_N4; i += ZB * 256)
        zero4[i] = zv;
}

// ---------------- CSR build ----------------

__global__ __launch_bounds__(1024) void scan1_k(const int* __restrict__ cnt,
                                                int* __restrict__ excl,
                                                int* __restrict__ aux) {
    __shared__ int wsum[16];
    int tid = threadIdx.x;
    int gid = blockIdx.x * 1024 + tid;
    int lane = tid & 63, wid = tid >> 6;
    int v = (gid < NN) ? cnt[gid] : 0;
    int x = v;
#pragma unroll
    for (int off = 1; off < 64; off <<= 1) {
        int t = __shfl_up(x, off, 64);
        if (lane >= off) x += t;
    }
    if (lane == 63) wsum[wid] = x;
    __syncthreads();
    if (wid == 0 && lane < 16) {
        int y = wsum[lane];
#pragma unroll
        for (int off = 1; off < 16; off <<= 1) {
            int t = __shfl_up(y, off, 64);
            if (lane >= off) y += t;
        }
        wsum[lane] = y;
    }
    __syncthreads();
    int base = (wid > 0) ? wsum[wid - 1] : 0;
    int incl = base + x;
    if (gid < NN) excl[gid] = incl - v;
    if (tid == 1023) aux[blockIdx.x] = incl;
}

__global__ __launch_bounds__(256) void scatter_k(const int* __restrict__ srcp,
                                                 const int* __restrict__ dstp,
                                                 const int* __restrict__ excl,
                                                 const int* __restrict__ aux,
                                                 const int* __restrict__ rank,
                                                 int* __restrict__ row_ptr,
                                                 int* __restrict__ col,
                                                 int nblk) {
    __shared__ int auxs[64];
    if (threadIdx.x < 64) {
        int lane = threadIdx.x;
        int v = (lane < nblk) ? aux[lane] : 0;
        int x = v;
#pragma unroll
        for (int off = 1; off < 64; off <<= 1) {
            int t = __shfl_up(x, off, 64);
            if (lane >= off) x += t;
        }
        auxs[lane] = x - v;
    }
    __syncthreads();
    int e = blockIdx.x * 256 + threadIdx.x;
    if (e >= TE) return;
    if (e <= NN) row_ptr[e] = (e == NN) ? TE : excl[e] + auxs[e >> 10];
    int s, d;
    if (e < NE) { s = srcp[e]; d = dstp[e]; } else { s = e - NE; d = s; }
    col[excl[d] + auxs[d >> 10] + rank[e]] = s << 8;
}

// ---- packed pair store (fp32 path, layer 1): slot 4*dd holds (ch d, ch d+32) ----
__device__ __forceinline__ void store_xlp(char* xlp, int row, int c0, const float* a) {
    unsigned hsel = (unsigned)c0 >> 6;
    unsigned dd = (unsigned)c0 & 31;
    unsigned sub = (c0 & 32) ? 2u : 0u;
    char* q = xlp + (size_t)row * 256 + hsel * 128 + 4 * dd + sub;
#pragma unroll
    for (int j = 0; j < 4; ++j)
        *(unsigned short*)(q + 4 * j) = f2bf(a[j]);
}

// ---------------- init_k: gemm_dual (layer1) + wtrans + fused edge count ----------------

__global__ __launch_bounds__(256) void init_k(const float* __restrict__ x,
                                              const float* __restrict__ Wl1,
                                              const float* __restrict__ Wr1,
                                              char* __restrict__ xlp,
                                              char* __restrict__ xrp,
                                              const float* __restrict__ Wl2,
                                              const float* __restrict__ Wr2,
                                              const float* __restrict__ Wl3,
                                              const float* __restrict__ Wr3,
                                              unsigned short* __restrict__ wt2,
                                              unsigned short* __restrict__ wt3,
                                              const int* __restrict__ dst,
                                              int* __restrict__ cnt,
                                              int* __restrict__ rank) {
    __shared__ float xs[32][72];
    __shared__ float ws[32][260];
    int b = blockIdx.x;
    int tid = threadIdx.x;

    if (b >= GGRID) {
        int bb = b - GGRID;
        if (bb < WTB) {
            int idx = bb * 256 + tid;
            int l = idx >> 14;
            int rem = idx & 16383;
            int k = rem >> 8;
            int c = rem & 255;
            const float* W = (l == 0) ? (c < 128 ? Wl2 : Wr2) : (c < 128 ? Wl3 : Wr3);
            float v = W[k * 128 + (c & 127)];
            unsigned short* wt = (l == 0) ? wt2 : wt3;
            wt[c * 64 + k] = f2bf(v);
        } else {
            // fused count: cnt zeroed by preceding zero_k dispatch
            int e = (bb - WTB) * 256 + tid;
            if (e < TE) {
                int d = (e < NE) ? dst[e] : (e - NE);
                rank[e] = atomicAdd(&cnt[d], 1);
            }
        }
        return;
    }

    // ---- gemm_dual body (K=3) ----
    int row0 = b * 64;
    int row_t = (tid >> 5) * 8;
    int c0 = (tid & 31) * 4;
    const int K = 3;

    float acc0[8][4];
    float acc1[8][4];
#pragma unroll
    for (int i = 0; i < 8; ++i)
#pragma unroll
        for (int j = 0; j < 4; ++j) { acc0[i][j] = 0.f; acc1[i][j] = 0.f; }

    for (int i = tid; i < 64 * K; i += 256) {
        int r = i / K;
        int k = i - r * K;
        int row = row0 + r;
        xs[k][r] = (row < NN) ? x[(size_t)row * K + k] : 0.f;
    }
    for (int i = tid; i < K * 64; i += 256) {
        int k = i >> 6;
        int cq = i & 63;
        const float* srcp = (cq < 32) ? &Wl1[(size_t)k * 128 + cq * 4]
                                      : &Wr1[(size_t)k * 128 + (cq - 32) * 4];
        float4 v = *(const float4*)srcp;
        *(float4*)&ws[k][cq * 4] = v;
    }
    __syncthreads();
    for (int k = 0; k < K; ++k) {
        float4 a0 = *(float4*)&xs[k][row_t];
        float4 a1 = *(float4*)&xs[k][row_t + 4];
        float4 b0 = *(float4*)&ws[k][c0];
        float4 b1 = *(float4*)&ws[k][c0 + 128];
        float av[8] = {a0.x, a0.y, a0.z, a0.w, a1.x, a1.y, a1.z, a1.w};
        float bl[4] = {b0.x, b0.y, b0.z, b0.w};
        float br[4] = {b1.x, b1.y, b1.z, b1.w};
#pragma unroll
        for (int i = 0; i < 8; ++i)
#pragma unroll
            for (int j = 0; j < 4; ++j) {
                acc0[i][j] += av[i] * bl[j];
                acc1[i][j] += av[i] * br[j];
            }
    }
#pragma unroll
    for (int i = 0; i < 8; ++i) {
        int row = row0 + row_t + i;
        if (row < NN) {
            store_xlp(xlp, row, c0, acc0[i]);
            store_xlp(xrp, row, c0, acc1[i]);   // xr packed bf16, same layout as xlp
        }
    }
}

// ---- shared helper: reduce 64 stat buckets -> cf[128] ----
__device__ __forceinline__ void reduce_stats(const float* __restrict__ stats,
                                             const float* __restrict__ gw,
                                             const float* __restrict__ gb,
                                             const float* __restrict__ gm,
                                             float (*part)[128],
                                             float* __restrict__ cf_out) {
    int tid = threadIdx.x;
    int w = tid >> 6;
    int lane = tid & 63;
    float s = 0.f, s2 = 0.f;
    for (int b = 16 * w; b < 16 * w + 16; ++b) {
        s += stats[b * 128 + lane];
        s2 += stats[b * 128 + 64 + lane];
    }
    part[w][lane] = s;
    part[w][64 + lane] = s2;
    __syncthreads();
    if (tid < 64) {
        int c = tid;
        float sum = (part[0][c] + part[1][c]) + (part[2][c] + part[3][c]);
        float sum2 = (part[0][64 + c] + part[1][64 + c]) + (part[2][64 + c] + part[3][64 + c]);
        float inv_n = 1.f / (float)NN;
        float mu = sum * inv_n;
        float ex2 = sum2 * inv_n;
        float g = gm[c];
        float var = ex2 - 2.f * g * mu * mu + g * g * mu * mu;
        float rs = rsqrtf(var + EPSV);
        cf_out[c] = gw[c] * rs;
        cf_out[64 + c] = gb[c] - gw[c] * rs * g * mu;
    }
    __syncthreads();
}

// ---------------- MFMA bf16 GEMM; h input is packed bf16 (col c, c+32 per uint) ----------------

__global__ __launch_bounds__(256) void gemm_mfma(const unsigned* __restrict__ hbf,
                                                 const float* __restrict__ stats,
                                                 const float* __restrict__ gw,
                                                 const float* __restrict__ gb,
                                                 const float* __restrict__ gm,
                                                 const unsigned short* __restrict__ wt,
                                                 char* __restrict__ xlp,
                                                 char* __restrict__ xrp,
                                                 int n) {
    __shared__ unsigned short xs[64][72];
    __shared__ float part[4][128];
    __shared__ float cfS[128];
    int tid = threadIdx.x;
    int row0 = blockIdx.x * 64;

    reduce_stats(stats, gw, gb, gm, part, cfS);

    {
        int r = tid >> 2;
        int q = tid & 3;
        int row = row0 + r;
        unsigned pk[8];
        if (row < n) {
            const unsigned* hp = hbf + (size_t)row * 32 + (q & 1) * 16;
            uint4 u0 = *(const uint4*)(hp + 0);
            uint4 u1 = *(const uint4*)(hp + 4);
            uint4 u2 = *(const uint4*)(hp + 8);
            uint4 u3 = *(const uint4*)(hp + 12);
            unsigned hv[16] = {u0.x, u0.y, u0.z, u0.w, u1.x, u1.y, u1.z, u1.w,
                               u2.x, u2.y, u2.z, u2.w, u3.x, u3.y, u3.z, u3.w};
            bool hi = (q >> 1) != 0;
#pragma unroll
            for (int i = 0; i < 4; ++i) {
                float4 v;
                v.x = hi ? __uint_as_float(hv[4 * i + 0] & 0xffff0000u) : __uint_as_float(hv[4 * i + 0] << 16);
                v.y = hi ? __uint_as_float(hv[4 * i + 1] & 0xffff0000u) : __uint_as_float(hv[4 * i + 1] << 16);
                v.z = hi ? __uint_as_float(hv[4 * i + 2] & 0xffff0000u) : __uint_as_float(hv[4 * i + 2] << 16);
                v.w = hi ? __uint_as_float(hv[4 * i + 3] & 0xffff0000u) : __uint_as_float(hv[4 * i + 3] << 16);
                float4 cw = *(const float4*)&cfS[q * 16 + 4 * i];
                float4 cb = *(const float4*)&cfS[64 + q * 16 + 4 * i];
                float r0 = fmaxf(fmaf(cw.x, v.x, cb.x), 0.f);
                float r1 = fmaxf(fmaf(cw.y, v.y, cb.y), 0.f);
                float r2 = fmaxf(fmaf(cw.z, v.z, cb.z), 0.f);
                float r3 = fmaxf(fmaf(cw.w, v.w, cb.w), 0.f);
                pk[2 * i]     = (unsigned)f2bf(r0) | ((unsigned)f2bf(r1) << 16);
                pk[2 * i + 1] = (unsigned)f2bf(r2) | ((unsigned)f2bf(r3) << 16);
            }
        } else {
#pragma unroll
            for (int i = 0; i < 8; ++i) pk[i] = 0;
        }
        uint4* dst = (uint4*)&xs[r][q * 16];
        dst[0] = make_uint4(pk[0], pk[1], pk[2], pk[3]);
        dst[1] = make_uint4(pk[4], pk[5], pk[6], pk[7]);
    }
    __syncthreads();

    int w = tid >> 6;
    int lane = tid & 63;
    int m = lane & 15;
    int quad = lane >> 4;

    BfU a0, a1;
    a0.u = *(const uint4*)&xs[16 * w + m][quad * 8];
    a1.u = *(const uint4*)&xs[16 * w + m][32 + quad * 8];

    const char* wtb = (const char*)wt + (size_t)(m * 128 + quad * 16);

    f32x4 acc[16];
#pragma unroll
    for (int c = 0; c < 16; ++c) acc[c] = (f32x4){0.f, 0.f, 0.f, 0.f};
#pragma unroll
    for (int c = 0; c < 16; ++c) {
        BfU b0, b1;
        b0.u = *(const uint4*)(wtb + c * 2048);
        b1.u = *(const uint4*)(wtb + c * 2048 + 64);
        acc[c] = __builtin_amdgcn_mfma_f32_16x16x32_bf16(a0.b, b0.b, acc[c], 0, 0, 0);
        acc[c] = __builtin_amdgcn_mfma_f32_16x16x32_bf16(a1.b, b1.b, acc[c], 0, 0, 0);
    }

    int rbase = row0 + 16 * w + quad * 4;
    // xl (acc 0..7) and xr (acc 8..15) both stored packed: pair (c, c+2) -> (ch d, ch d+32)
#pragma unroll
    for (int pi = 0; pi < 4; ++pi) {
        int c = (pi & 1) + (pi >> 1) * 4;
        int head = pi >> 1;
        int dd = (pi & 1) * 16 + m;
#pragma unroll
        for (int r = 0; r < 4; ++r) {
            int row = rbase + r;
            if (row < n) {
                unsigned vl = (unsigned)f2bf(acc[c][r]) | ((unsigned)f2bf(acc[c + 2][r]) << 16);
                unsigned vr = (unsigned)f2bf(acc[c + 8][r]) | ((unsigned)f2bf(acc[c + 10][r]) << 16);
                *(unsigned*)(xlp + (size_t)row * 256 + head * 128 + 4 * dd) = vl;
                *(unsigned*)(xrp + (size_t)row * 256 + head * 128 + 4 * dd) = vr;
            }
        }
    }
}

// ---------------- coef_k: one block, stats buckets -> cf (for apply) ----------------

__global__ __launch_bounds__(256) void coef_k(const float* __restrict__ stats,
                                              const float* __restrict__ gw,
                                              const float* __restrict__ gb,
                                              const float* __restrict__ gm,
                                              float* __restrict__ cf) {
    __shared__ float part[4][128];
    reduce_stats(stats, gw, gb, gm, part, cf);
}

// ---------------- Attention: 16 lanes per edge, uint4 gather, packed bf16 xr ----------------
// lane layout: group g = lane>>4 owns edge slots 2g, 2g+1 of each 8-edge batch.
// t16 = lane&15: t16<8 -> head0, t16>=8 -> head1; each lane covers 8 channels:
// packed pairs (dd+j, dd+j+32), dd = (t16&7)*4, via one uint4 (16B of the row).
// xrp shares xlp's layout so xv unpacks in the same order as l[].
// per-head logit reduce over lane bits 0..2: bits 0,1 quad-local -> DPP adds
// (VALU pipe, no lgkmcnt); bit 2 -> one shfl_xor.

__device__ __forceinline__ void unpack8(uint4 q, float* l) {
    l[0] = __uint_as_float(q.x << 16);
    l[1] = __uint_as_float(q.x & 0xffff0000u);
    l[2] = __uint_as_float(q.y << 16);
    l[3] = __uint_as_float(q.y & 0xffff0000u);
    l[4] = __uint_as_float(q.z << 16);
    l[5] = __uint_as_float(q.z & 0xffff0000u);
    l[6] = __uint_as_float(q.w << 16);
    l[7] = __uint_as_float(q.w & 0xffff0000u);
}

// per-lane partial of logit: 0.6*sum(a*t) + 0.4*sum(a*|t|), t = l + xv
__device__ __forceinline__ float logit_part(const float* l, const float* xv, const float* av) {
    float u1 = 0.f, u2 = 0.f;
#pragma unroll
    for (int k = 0; k < 8; ++k) {
        float t = l[k] + xv[k];
        u1 = fmaf(av[k], t, u1);
        u2 = fmaf(av[k], fabsf(t), u2);
    }
    return fmaf(0.6f, u1, 0.4f * u2);
}

__device__ __forceinline__ float head_reduce(float x) {
    x += __int_as_float(__builtin_amdgcn_mov_dpp(__float_as_int(x), 0xB1, 0xF, 0xF, true)); // quad xor1
    x += __int_as_float(__builtin_amdgcn_mov_dpp(__float_as_int(x), 0x4E, 0xF, 0xF, true)); // quad xor2
    x += __shfl_xor(x, 4, 64);
    return x;
}

__device__ __forceinline__ void attn_pair(const char* __restrict__ xlp, int lp16,
                                          int off0, int off1, bool v0, bool v1,
                                          const float* xv, const float* av,
                                          float* o, float& zacc) {
    uint4 q0 = *(const uint4*)(xlp + (unsigned)(off0 + lp16));
    uint4 q1 = *(const uint4*)(xlp + (unsigned)(off1 + lp16));
    float l0[8], l1[8];
    unpack8(q0, l0);
    unpack8(q1, l1);
    float w0 = head_reduce(logit_part(l0, xv, av));
    float w1 = head_reduce(logit_part(l1, xv, av));
    float e0 = __expf(w0);
    float e1 = __expf(w1);
    if (!v0) e0 = 0.f;
    if (!v1) e1 = 0.f;
    zacc += e0 + e1;
#pragma unroll
    for (int k = 0; k < 8; ++k) o[k] = fmaf(e1, l1[k], fmaf(e0, l0[k], o[k]));
}

__global__ __launch_bounds__(256) void attn_k(const char* __restrict__ xlp,
                                              const char* __restrict__ xrp,
                                              const float* __restrict__ att,
                                              const float* __restrict__ bias,
                                              const int* __restrict__ row_ptr,
                                              const int* __restrict__ coloff,
                                              unsigned* __restrict__ hout,
                                              float* __restrict__ stats) {
    __shared__ float sb[4][64];
    int tid = threadIdx.x;
    int lane = tid & 63;
    int wv = tid >> 6;
    int node = blockIdx.x * 4 + wv;       // grid == NN/4 exactly
    int t16 = lane & 15;
    int slot = (lane >> 4) * 2;
    int head = t16 >> 3;
    int dd = (t16 & 7) * 4;
    int lp16 = t16 * 16;
    int cbase = head * 64 + dd;

    float xv[8];
    unpack8(*(const uint4*)(xrp + ((size_t)node << 8) + lp16), xv);
    float4 a0 = *(const float4*)(att + cbase);
    float4 a1 = *(const float4*)(att + cbase + 32);
    float av[8] = {a0.x, a1.x, a0.y, a1.y, a0.z, a1.z, a0.w, a1.w};

    float o[8];
#pragma unroll
    for (int k = 0; k < 8; ++k) o[k] = 0.f;
    float zacc = 0.f;

    int beg = __builtin_amdgcn_readfirstlane(row_ptr[node]);
    int end = __builtin_amdgcn_readfirstlane(row_ptr[node + 1]);

    int idx = beg;
    for (; idx + 8 <= end; idx += 8) {
        int off0 = coloff[idx + slot];
        int off1 = coloff[idx + slot + 1];
        attn_pair(xlp, lp16, off0, off1, true, true, xv, av, o, zacc);
    }
    if (idx < end) {
        int e1 = end - 1;
        int i0 = idx + slot, i1 = idx + slot + 1;
        int off0 = coloff[min(i0, e1)];
        int off1 = coloff[min(i1, e1)];
        attn_pair(xlp, lp16, off0, off1, i0 < end, i1 < end, xv, av, o, zacc);
    }

    // cross-group (bits 4,5) reduce for z and o; heads stay separate (bit 3)
    float z = zacc + __shfl_xor(zacc, 16, 64);
    z += __shfl_xor(z, 32, 64);
    float zi = 1.0f / z;
    float r[8];
#pragma unroll
    for (int k = 0; k < 8; ++k) {
        float v = o[k] + __shfl_xor(o[k], 16, 64);
        v += __shfl_xor(v, 32, 64);
        v *= zi;
        float p = __shfl_xor(v, 8, 64);   // partner head, same channels (l-order pairs)
        r[k] = 0.5f * (v + p);
    }
    if (lane < 8) {
        // r[] is in l-order: even k -> head0 ch dd+k/2, odd k -> head1 ch dd+k/2
        float4 b0 = *(const float4*)(bias + dd);
        float4 b1 = *(const float4*)(bias + dd + 32);
        float rl0 = r[0] + b0.x, rl1 = r[2] + b0.y, rl2 = r[4] + b0.z, rl3 = r[6] + b0.w;
        float rh0 = r[1] + b1.x, rh1 = r[3] + b1.y, rh2 = r[5] + b1.z, rh3 = r[7] + b1.w;
        unsigned pk0 = (unsigned)f2bf(rl0) | ((unsigned)f2bf(rh0) << 16);
        unsigned pk1 = (unsigned)f2bf(rl1) | ((unsigned)f2bf(rh1) << 16);
        unsigned pk2 = (unsigned)f2bf(rl2) | ((unsigned)f2bf(rh2) << 16);
        unsigned pk3 = (unsigned)f2bf(rl3) | ((unsigned)f2bf(rh3) << 16);
        *(uint4*)&hout[(size_t)node * 32 + dd] = make_uint4(pk0, pk1, pk2, pk3);
        *(float4*)&sb[wv][dd] = make_float4(rl0, rl1, rl2, rl3);
        *(float4*)&sb[wv][dd + 32] = make_float4(rh0, rh1, rh2, rh3);
    }
    __syncthreads();
    if (tid < 64) {
        int c = tid;
        float v0 = sb[0][c], v1 = sb[1][c], v2 = sb[2][c], v3 = sb[3][c];
        float s = (v0 + v1) + (v2 + v3);
        float s2 = fmaf(v0, v0, v1 * v1) + fmaf(v2, v2, v3 * v3);
        float* bkt = stats + (size_t)(blockIdx.x & (NBUCK - 1)) * 128;
        atomicAdd(&bkt[c], s);
        atomicAdd(&bkt[64 + c], s2);
    }
}

// ---------------- final GraphNorm apply + ReLU (unpack bf16 h, fp32 out) ----------------

__global__ __launch_bounds__(256) void apply_k(const unsigned* __restrict__ h,
                                               const float* __restrict__ cf,
                                               float* __restrict__ y) {
    int i = blockIdx.x * 256 + threadIdx.x;   // uint4 index, total NN*8
    if (i >= NN * 8) return;
    int node = i >> 3;
    int j = (i & 7) * 4;                      // laneh base 0,4,...,28
    uint4 u = *(const uint4*)(h + (size_t)node * 32 + j);
    float4 lo, hi;
    lo.x = __uint_as_float(u.x << 16); hi.x = __uint_as_float(u.x & 0xffff0000u);
    lo.y = __uint_as_float(u.y << 16); hi.y = __uint_as_float(u.y & 0xffff0000u);
    lo.z = __uint_as_float(u.z << 16); hi.z = __uint_as_float(u.z & 0xffff0000u);
    lo.w = __uint_as_float(u.w << 16); hi.w = __uint_as_float(u.w & 0xffff0000u);
    float4 cwl = *(const float4*)&cf[j];
    float4 cbl = *(const float4*)&cf[64 + j];
    float4 cwh = *(const float4*)&cf[32 + j];
    float4 cbh = *(const float4*)&cf[96 + j];
    float4 rl, rh;
    rl.x = fmaxf(fmaf(cwl.x, lo.x, cbl.x), 0.f);
    rl.y = fmaxf(fmaf(cwl.y, lo.y, cbl.y), 0.f);
    rl.z = fmaxf(fmaf(cwl.z, lo.z, cbl.z), 0.f);
    rl.w = fmaxf(fmaf(cwl.w, lo.w, cbl.w), 0.f);
    rh.x = fmaxf(fmaf(cwh.x, hi.x, cbh.x), 0.f);
    rh.y = fmaxf(fmaf(cwh.y, hi.y, cbh.y), 0.f);
    rh.z = fmaxf(fmaf(cwh.z, hi.z, cbh.z), 0.f);
    rh.w = fmaxf(fmaf(cwh.w, hi.w, cbh.w), 0.f);
    *(float4*)&y[(size_t)node * 64 + j] = rl;
    *(float4*)&y[(size_t)node * 64 + 32 + j] = rh;
}

// ---------------- launch ----------------

extern "C" void kernel_launch(void* const* d_in, const int* in_sizes, int n_in,
                              void* d_out, int out_size, void* d_ws, size_t ws_size,
                              hipStream_t stream) {
    const float* x0 = (const float*)d_in[0];
    const int* ei = (const int*)d_in[1];
    const int* srcp = ei;
    const int* dstp = ei + NE;

    const float* Wl[3], *Wr[3], *att[3], *bv[3], *gw[3], *gb[3], *gm[3];
    for (int l = 0; l < 3; ++l) {
        int base = 2 + 7 * l;
        Wl[l] = (const float*)d_in[base + 0];
        Wr[l] = (const float*)d_in[base + 1];
        att[l] = (const float*)d_in[base + 2];
        bv[l] = (const float*)d_in[base + 3];
        gw[l] = (const float*)d_in[base + 4];
        gb[l] = (const float*)d_in[base + 5];
        gm[l] = (const float*)d_in[base + 6];
    }

    char* p = (char*)d_ws;
    auto take = [&](size_t bytes) -> void* {
        void* r = (void*)p;
        p += (bytes + 255) & ~(size_t)255;
        return r;
    };
    char* xlp = (char*)take((size_t)NN * 256);
    char* xrp = (char*)take((size_t)NN * 256);             // packed bf16, same layout as xlp
    unsigned* hb = (unsigned*)take((size_t)NN * 32 * 4);   // packed bf16 hidden state
    char* zr = (char*)take(298304);
    float* stats = (float*)zr;
    int* cnt = (int*)(zr + 98304);
    int* excl = (int*)take((size_t)NN * 4);
    int* row_ptr = (int*)take((size_t)(NN + 1) * 4);
    int* rank = (int*)take((size_t)TE * 4);
    int* col = (int*)take((size_t)TE * 4);
    int* aux = (int*)take(64 * 4);
    float* cf3 = (float*)take(128 * 4);
    unsigned short* wt2 = (unsigned short*)take(16384 * 2);
    unsigned short* wt3 = (unsigned short*)take(16384 * 2);

    int nblk = (NN + 1023) / 1024;
    int egrid = (TE + 255) / 256;

    zero_k<<<ZB, 256, 0, stream>>>((float4*)zr);
    init_k<<<GGRID + WTB + CB, 256, 0, stream>>>(x0, Wl[0], Wr[0], xlp, xrp,
                                                 Wl[1], Wr[1], Wl[2], Wr[2],
                                                 wt2, wt3, dstp, cnt, rank);
    scan1_k<<<nblk, 1024, 0, stream>>>(cnt, excl, aux);
    scatter_k<<<egrid, 256, 0, stream>>>(srcp, dstp, excl, aux, rank, row_ptr, col, nblk);

    int ggrid = (NN + 63) / 64;
    int agrid = NN / 4;   // exact
    for (int l = 0; l < 3; ++l) {
        if (l > 0)
            gemm_mfma<<<ggrid, 256, 0, stream>>>(hb, stats + (size_t)(l - 1) * NBUCK * 128,
                                                 gw[l - 1], gb[l - 1], gm[l - 1],
                                                 (l == 1) ? wt2 : wt3, xlp, xrp, NN);
        attn_k<<<agrid, 256, 0, stream>>>(xlp, xrp, att[l], bv[l], row_ptr, col, hb,
                                          stats + (size_t)l * NBUCK * 128);
    }
    coef_k<<<1, 256, 0, stream>>>(stats + (size_t)2 * NBUCK * 128, gw[2], gb[2], gm[2], cf3);
    apply_k<<<(NN * 8 + 255) / 256, 256, 0, stream>>>(hb, cf3, (float*)d_out);
}